// Round 1
// baseline (204.881 us; speedup 1.0000x reference)
//
#include <hip/hip_runtime.h>
#include <hip/hip_bf16.h>
#include <stdint.h>

typedef unsigned short u16;
typedef unsigned int   u32;

#define N_DIM  1024
#define IN_DIM 1024
#define H_DIM  64
#define BATCH  16

typedef __bf16 bf16x8 __attribute__((ext_vector_type(8)));
typedef float  f32x4  __attribute__((ext_vector_type(4)));

// round-to-nearest-even fp32 -> bf16 (bit pattern)
__device__ inline u16 f2bf(float f) {
    union { float f; u32 u; } v; v.f = f;
    u32 u = v.u;
    return (u16)((u + 0x7fffu + ((u >> 16) & 1u)) >> 16);
}
// packed pair: v_cvt_pk_bf16_f32 when available
__device__ inline u32 pack2(float a, float b) {
    __hip_bfloat162 h = __float22bfloat162_rn(float2{a, b});
    union { __hip_bfloat162 h; u32 u; } cv; cv.h = h; return cv.u;
}

// async global->LDS, 16B per lane. LDS dest must be wave-uniform base + lane*16.
__device__ inline void gl_lds16(const u16* g, u16* l) {
    __builtin_amdgcn_global_load_lds(
        (const __attribute__((address_space(1))) u32*)g,
        (__attribute__((address_space(3))) u32*)l, 16, 0, 0);
}

// ---------------------------------------------------------------------------
// prep_w: QT[h][i] = bf16(Q[i][h]); KwT[h][n] = bf16(Kw[n][h])
__global__ void prep_w(const float* __restrict__ Q, const float* __restrict__ Kw,
                       u16* __restrict__ QT, u16* __restrict__ KwT) {
    int idx = blockIdx.x * 256 + threadIdx.x;           // 0 .. 131071
    const float* src = (idx < 65536) ? Q : Kw;
    u16* dst = (idx < 65536) ? QT : KwT;
    int i = idx & 65535;
    int h = i >> 10;         // 0..63
    int n = i & 1023;        // 0..1023 (contiguous store)
    dst[h * 1024 + n] = f2bf(src[n * 64 + h]);
}

// prep_g: Gbt[j][i] = bf16(G[i][j]) (tiled transpose) + Grsum[i] = sum_j G[i][j]
__global__ void prep_g(const float* __restrict__ G, u16* __restrict__ Gbt,
                       float* __restrict__ Grsum) {
    __shared__ float tile[64][65];
    int i0 = blockIdx.y * 64, j0 = blockIdx.x * 64;
    int tx = threadIdx.x & 63, ty = threadIdx.x >> 6;   // ty 0..3
    for (int r = 0; r < 16; ++r) {
        int i = ty * 16 + r;
        tile[i][tx] = G[(size_t)(i0 + i) * 1024 + j0 + tx];
    }
    __syncthreads();
    for (int r = 0; r < 16; ++r) {
        int j = ty * 16 + r;
        Gbt[(size_t)(j0 + j) * 1024 + i0 + tx] = f2bf(tile[tx][j]);
    }
    if (ty == 0) {
        float sum = 0.f;
        for (int j = 0; j < 64; ++j) sum += tile[tx][j];
        atomicAdd(&Grsum[i0 + tx], sum);
    }
}

// ---------------------------------------------------------------------------
// gemm_q: q[b][n][h] = sum_i s[n][b][i] * Qw[i][h], bf16 out, single pass.
// Grid (16 n-tiles, 16 b), 512 thr = 8 waves. Waves 0-3: i in [0,512),
// waves 4-7: i in [512,1024); same 16-row m-quarter per (w&3). Full K per
// block, no partials: cross-half fp32 reduce through 16 KB LDS at the end.
// A-frags built in registers from coalesced 32B row reads (no LDS staging,
// no barriers in main loop). B-frags direct from L2-resident QT[h][i].
// Depth-2 register prefetch pipelines the loads under MFMA.
__global__ __launch_bounds__(512) void gemm_q(
        const float* __restrict__ s, const u16* __restrict__ QT,
        u16* __restrict__ qws) {
    int b = blockIdx.y;
    int n0 = blockIdx.x * 64;
    __shared__ __align__(16) float red[4096];          // 16 KB reduce buffer
    int t = threadIdx.x, lane = t & 63, w = t >> 6, quad = lane >> 4, l15 = lane & 15;
    int wm = (w & 3) * 16;                             // m-quarter within 64
    int kb = (w >> 2) * 512;                           // k-half
    const float* arow = s + (size_t)(n0 + wm + l15) * (BATCH * IN_DIM)
                          + (size_t)b * IN_DIM + kb + quad * 8;
    const u16* bbase = QT + (size_t)l15 * 1024 + kb + quad * 8;

    f32x4 acc[4] = {};
    float4 A0[2], A1[2];
    bf16x8 Bf[2][4];
    A0[0] = ((const float4*)arow)[0];
    A1[0] = ((const float4*)arow)[1];
#pragma unroll
    for (int ct = 0; ct < 4; ++ct)
        Bf[0][ct] = *(const bf16x8*)&bbase[ct * 16384];

#pragma unroll
    for (int st = 0; st < 16; ++st) {                  // 16 steps of k=32
        int cur = st & 1, nxt = cur ^ 1;
        if (st < 15) {
            const float4* ap = (const float4*)(arow + (size_t)(st + 1) * 32);
            A0[nxt] = ap[0];
            A1[nxt] = ap[1];
#pragma unroll
            for (int ct = 0; ct < 4; ++ct)
                Bf[nxt][ct] = *(const bf16x8*)&bbase[ct * 16384 + (st + 1) * 32];
        }
        float4 fa = A0[cur], fb = A1[cur];
        union { uint4 u; bf16x8 v; } cu;
        cu.u = (uint4){ pack2(fa.x, fa.y), pack2(fa.z, fa.w),
                        pack2(fb.x, fb.y), pack2(fb.z, fb.w) };
#pragma unroll
        for (int ct = 0; ct < 4; ++ct)
            acc[ct] = __builtin_amdgcn_mfma_f32_16x16x32_bf16(cu.v, Bf[cur][ct], acc[ct], 0, 0, 0);
    }

    // cross-k-half reduce: upper waves park acc in LDS, lower waves add+store
    if (w >= 4) {
        float* dst = red + ((w - 4) * 64 + lane) * 16;
#pragma unroll
        for (int ct = 0; ct < 4; ++ct) *(f32x4*)&dst[ct * 4] = acc[ct];
    }
    __syncthreads();
    if (w < 4) {
        const float* sp2 = red + (w * 64 + lane) * 16;
        u16* ob = qws + (size_t)b * 65536;
#pragma unroll
        for (int ct = 0; ct < 4; ++ct) {
            f32x4 o = *(const f32x4*)&sp2[ct * 4];
#pragma unroll
            for (int r = 0; r < 4; ++r) {
                int m = n0 + wm + quad * 4 + r;
                ob[(size_t)m * 64 + ct * 16 + l15] = f2bf(acc[ct][r] + o[r]);
            }
        }
    }
}

// ---------------------------------------------------------------------------
// gemm_kt: kt[b][i][h] = sum_n s[n][b][i] * Kw[n][h], bf16 out, single pass.
// Grid (16 i-tiles, 16 b), 512 thr = 8 waves. Contraction over n is COMPLETE
// per block (grid over i), so no global partials. Waves 0-3: n in [0,512),
// waves 4-7: n in [512,1024); fp32 LDS reduce at the end (aliases As).
// Per 32-n chunk: coalesced 32B/thread row reads, transpose-cast into
// As[i][n] bf16 (pitch 34: ~2-way write banks, free), double-buffered with
// one barrier per chunk and 2-chunk-deep register prefetch of s.
// A-frag read is 4x ds_read_b32 (pitch 34 breaks 16B alignment; b32 is
// conflict-clean at stride 17 dwords). B-frags direct from L2-resident KwT.
__global__ __launch_bounds__(512) void gemm_kt(
        const float* __restrict__ s, const u16* __restrict__ KwT,
        u16* __restrict__ ktws) {
    int b = blockIdx.y;
    int i0 = blockIdx.x * 64;
    __shared__ __align__(16) u16 As[2][2][64][34];     // [half][buf][i][n+pad] = 17408 B
    int t = threadIdx.x, lane = t & 63, w = t >> 6, quad = lane >> 4, l15 = lane & 15;
    int half = w >> 2;                                 // compute n-half
    int wm = (w & 3) * 16;                             // i-quarter
    int shalf = t >> 8, nr = (t & 255) >> 3, iofs = (t & 7) * 8;  // staging role
    const float* sp = s + (size_t)(shalf * 512 + nr) * (BATCH * IN_DIM)
                        + (size_t)b * IN_DIM + i0 + iofs;
    const u16* bbase = KwT + (size_t)l15 * 1024 + half * 512 + quad * 8;

    f32x4 acc[4] = {};
    float4 P0[2], P1[2];
    bf16x8 Bf[2][4];
    P0[0] = ((const float4*)sp)[0];
    P1[0] = ((const float4*)sp)[1];
    {
        const float4* p = (const float4*)(sp + (size_t)32 * 16384);
        P0[1] = p[0]; P1[1] = p[1];
    }
#pragma unroll
    for (int ct = 0; ct < 4; ++ct)
        Bf[0][ct] = *(const bf16x8*)&bbase[ct * 16384];

#pragma unroll
    for (int c = 0; c < 16; ++c) {                     // 16 chunks of n=32 per half
        int buf = c & 1;
        // transpose-cast chunk c from regs into As[shalf][buf]
        float4 fa = P0[buf], fb = P1[buf];
        u16* wp = &As[shalf][buf][iofs][nr];
        wp[0]   = f2bf(fa.x);
        wp[34]  = f2bf(fa.y);
        wp[68]  = f2bf(fa.z);
        wp[102] = f2bf(fa.w);
        wp[136] = f2bf(fb.x);
        wp[170] = f2bf(fb.y);
        wp[204] = f2bf(fb.z);
        wp[238] = f2bf(fb.w);
        __syncthreads();                               // As[buf] ready (both halves)
        if (c < 14) {                                  // prefetch chunk c+2
            const float4* p = (const float4*)(sp + (size_t)(c + 2) * 32 * 16384);
            P0[buf] = p[0]; P1[buf] = p[1];
        }
        if (c < 15) {                                  // prefetch next B-frags (L2)
#pragma unroll
            for (int ct = 0; ct < 4; ++ct)
                Bf[(c + 1) & 1][ct] = *(const bf16x8*)&bbase[ct * 16384 + (c + 1) * 32];
        }
        const u32* ap = (const u32*)&As[half][buf][wm + l15][quad * 8];
        union { u32 u[4]; bf16x8 v; } au;
        au.u[0] = ap[0]; au.u[1] = ap[1]; au.u[2] = ap[2]; au.u[3] = ap[3];
#pragma unroll
        for (int ct = 0; ct < 4; ++ct)
            acc[ct] = __builtin_amdgcn_mfma_f32_16x16x32_bf16(au.v, Bf[buf][ct], acc[ct], 0, 0, 0);
    }

    __syncthreads();                                   // staging reads all done
    float* red = (float*)As;                           // alias: 16 KB <= 17408 B
    if (w >= 4) {
        float* dst = red + ((w - 4) * 64 + lane) * 16;
#pragma unroll
        for (int ct = 0; ct < 4; ++ct) *(f32x4*)&dst[ct * 4] = acc[ct];
    }
    __syncthreads();
    if (w < 4) {
        const float* sp2 = red + (w * 64 + lane) * 16;
        u16* ob = ktws + (size_t)b * 65536;
#pragma unroll
        for (int ct = 0; ct < 4; ++ct) {
            f32x4 o = *(const f32x4*)&sp2[ct * 4];
#pragma unroll
            for (int r = 0; r < 4; ++r) {
                int i = i0 + wm + quad * 4 + r;
                ob[(size_t)i * 64 + ct * 16 + l15] = f2bf(acc[ct][r] + o[r]);
            }
        }
    }
}

// ---------------------------------------------------------------------------
// gemm_fused (BN=256): per (b, m-tile 128, n-tile 256):
//   K-loop over i (32/step): score chunk S^T(32i x 128m) = kt_chunk @ q^T (MFMA),
//   square(+1e-9), rowsum via Grsum identity, pack bf16 -> As (padded), then
//   agg k-step: acc += As(128x32) @ Gbt-chunk(256 rows). Epilogue: scale by
//   1/(rowsum+1e-3), write transposed (n,B,j) fp32 output. att never hits HBM.
// Score redundancy is 4x (vs 8x at BN=128); epilogue VALU per output halves.
__global__ __launch_bounds__(256, 2) void gemm_fused(
        const u16* __restrict__ qws, const u16* __restrict__ ktws,
        const u16* __restrict__ Gbt, const float* __restrict__ Grsum,
        float* __restrict__ out) {
    int b = blockIdx.z;
    int n0 = blockIdx.x * 256, m0 = blockIdx.y * 128;
    const u16* qb = qws  + (size_t)b * 65536;
    const u16* kb = ktws + (size_t)b * 65536;
    __shared__ __align__(16) u16 As[128 * 40];       // score->agg buffer, padded
    __shared__ __align__(16) u16 Bs[2][256 * 32];    // Gbt staging (gl_lds, dbuf)
    __shared__ __align__(16) u16 ktc[32 * 72];       // kt chunk, padded, single buf
    __shared__ __align__(16) float Grs[1024];
    __shared__ float rs[128];
    int t = threadIdx.x, lane = t & 63, w = t >> 6, quad = lane >> 4, l15 = lane & 15;
    int ti = w & 1;                              // score i-subtile (16 of 32)
    int wm = (w >> 1) * 64;                      // m-half (shared by score & agg)
    int wn = (w & 1) * 128;                      // agg n-half of 256

    ((float4*)Grs)[t] = ((const float4*)Grsum)[t];
    if (t < 128) rs[t] = 0.f;

    // K-invariant q B-frags: B[k=h][col=m], 8 contiguous h per lane
    bf16x8 qf[4][2];
    for (int j = 0; j < 4; ++j)
        for (int kick = 0; kick < 2; ++kick)
            qf[j][kick] = *(const bf16x8*)&qb[(size_t)(m0 + wm + j*16 + l15) * 64 + kick*32 + quad*8];

    // iter-0 staging: Gbt rows n0..n0+255, 32 cols
    int br = t >> 2, bc = (t & 3) * 8;
    for (int g4 = 0; g4 < 4; ++g4)
        gl_lds16(Gbt + (size_t)(n0 + br + g4*64) * 1024 + bc, &Bs[0][(br + g4*64) * 32 + bc]);
    int ir = t >> 3, ch = (t & 7) * 8;
    uint4 kreg = *(const uint4*)&kb[(size_t)ir * 64 + ch];

    f32x4 acc[4][8] = {};
    float partial[4] = {0.f, 0.f, 0.f, 0.f};

    for (int kk = 0; kk < 32; ++kk) {
        int buf = kk & 1;
        *(uint4*)&ktc[ir * 72 + ch] = kreg;        // single buf: prev reads done pre-barrier2
        __syncthreads();                           // barrier1: Bs[buf] + ktc ready
        // ---- score: S^T[i][m] for i-subtile ti, m in wave's 64-half
        f32x4 sacc[4] = {};
        for (int kick = 0; kick < 2; ++kick) {
            bf16x8 ktf = *(const bf16x8*)&ktc[(ti*16 + l15) * 72 + kick*32 + quad*8];
            for (int j = 0; j < 4; ++j)
                sacc[j] = __builtin_amdgcn_mfma_f32_16x16x32_bf16(ktf, qf[j][kick], sacc[j], 0, 0, 0);
        }
        if (kk < 31)
            kreg = *(const uint4*)&kb[(size_t)((kk + 1) * 32 + ir) * 64 + ch];
        // ---- epilogue: square, rowsum partial, pack to As
        float4 g = *(const float4*)&Grs[kk * 32 + ti * 16 + quad * 4];
        for (int j = 0; j < 4; ++j) {
            float v0 = sacc[j][0] * 0.125f + 1e-9f; v0 *= v0;
            float v1 = sacc[j][1] * 0.125f + 1e-9f; v1 *= v1;
            float v2 = sacc[j][2] * 0.125f + 1e-9f; v2 *= v2;
            float v3 = sacc[j][3] * 0.125f + 1e-9f; v3 *= v3;
            partial[j] += v0 * g.x + v1 * g.y + v2 * g.z + v3 * g.w;
            uint2 pk = { pack2(v0, v1), pack2(v2, v3) };
            *(uint2*)&As[(wm + j*16 + l15) * 40 + ti*16 + quad*4] = pk;
        }
        __syncthreads();                           // barrier2: As ready
        if (kk < 31) {                             // prefetch next Gbt chunk (in flight across agg)
            for (int g4 = 0; g4 < 4; ++g4)
                gl_lds16(Gbt + (size_t)(n0 + br + g4*64) * 1024 + (kk+1)*32 + bc,
                         &Bs[buf^1][(br + g4*64) * 32 + bc]);
        }
        // ---- agg k-step: wave's 64m x 128n
        int kh = quad * 8;
        bf16x8 af[4];
        for (int i = 0; i < 4; ++i) af[i] = *(const bf16x8*)&As[(wm + i*16 + l15) * 40 + kh];
        for (int jh = 0; jh < 2; ++jh) {
            bf16x8 bfr[4];
            for (int j = 0; j < 4; ++j)
                bfr[j] = *(const bf16x8*)&Bs[buf][(wn + jh*64 + j*16 + l15) * 32 + kh];
            for (int i = 0; i < 4; ++i)
                for (int j = 0; j < 4; ++j)
                    acc[i][jh*4 + j] = __builtin_amdgcn_mfma_f32_16x16x32_bf16(af[i], bfr[j], acc[i][jh*4 + j], 0, 0, 0);
        }
    }

    // rowsum: reduce quads (same m, different i-subsets), combine waves via LDS
    for (int j = 0; j < 4; ++j) {
        partial[j] += __shfl_xor(partial[j], 16, 64);
        partial[j] += __shfl_xor(partial[j], 32, 64);
    }
    if (quad == 0)
        for (int j = 0; j < 4; ++j) atomicAdd(&rs[wm + j*16 + l15], partial[j]);
    __syncthreads();
    if (t < 128) rs[t] = 1.0f / (rs[t] + 0.001f);
    __syncthreads();

    for (int i = 0; i < 4; ++i) {
        float4 rv = *(const float4*)&rs[wm + i * 16 + quad * 4];
        float rva[4] = { rv.x, rv.y, rv.z, rv.w };
        for (int r = 0; r < 4; ++r) {
            int m = m0 + wm + i * 16 + quad * 4 + r;
            float* orow = out + (size_t)m * (BATCH * IN_DIM) + (size_t)b * IN_DIM + n0 + wn;
            for (int j = 0; j < 8; ++j)
                orow[j * 16 + l15] = acc[i][j][r] * rva[r];
        }
    }
}

// ---------------------------------------------------------------------------
extern "C" void kernel_launch(void* const* d_in, const int* in_sizes, int n_in,
                              void* d_out, int out_size, void* d_ws, size_t ws_size,
                              hipStream_t stream) {
    const float* s  = (const float*)d_in[0];
    const float* G  = (const float*)d_in[1];
    const float* Q  = (const float*)d_in[2];
    const float* Kw = (const float*)d_in[3];
    float* out = (float*)d_out;
    char* ws = (char*)d_ws;

    // (first 32 MB previously held split-K partials -- now unused)
    u16*   qws   = (u16*)(ws + (size_t)(32u << 20));              // 2 MB
    u16*   ktws  = qws + (size_t)16 * 65536;                      // 2 MB
    u16*   Gbt   = (u16*)(ws + (size_t)(36u << 20));              // 2 MB
    u16*   QT    = (u16*)(ws + (size_t)(38u << 20));              // 128 KB
    u16*   KwT   = (u16*)(ws + (size_t)(38u << 20) + (128u << 10)); // 128 KB
    float* Grsum = (float*)(ws + (size_t)(38u << 20) + (256u << 10)); // 4 KB

    hipMemsetAsync(Grsum, 0, 1024 * sizeof(float), stream);
    prep_w<<<512, 256, 0, stream>>>(Q, Kw, QT, KwT);
    prep_g<<<dim3(16, 16), 256, 0, stream>>>(G, Gbt, Grsum);
    gemm_q<<<dim3(16, 16), 512, 0, stream>>>(s, QT, qws);
    gemm_kt<<<dim3(16, 16), 512, 0, stream>>>(s, KwT, ktws);
    gemm_fused<<<dim3(4, 8, 16), 256, 0, stream>>>(qws, ktws, Gbt, Grsum, out);
}

// Round 2
// 197.518 us; speedup vs baseline: 1.0373x; 1.0373x over previous
//
#include <hip/hip_runtime.h>
#include <hip/hip_bf16.h>
#include <stdint.h>

typedef unsigned short u16;
typedef unsigned int   u32;

#define N_DIM  1024
#define IN_DIM 1024
#define H_DIM  64
#define BATCH  16

typedef __bf16 bf16x8 __attribute__((ext_vector_type(8)));
typedef float  f32x4  __attribute__((ext_vector_type(4)));

// round-to-nearest-even fp32 -> bf16 (bit pattern)
__device__ inline u16 f2bf(float f) {
    union { float f; u32 u; } v; v.f = f;
    u32 u = v.u;
    return (u16)((u + 0x7fffu + ((u >> 16) & 1u)) >> 16);
}
// packed pair: v_cvt_pk_bf16_f32 when available
__device__ inline u32 pack2(float a, float b) {
    __hip_bfloat162 h = __float22bfloat162_rn(float2{a, b});
    union { __hip_bfloat162 h; u32 u; } cv; cv.h = h; return cv.u;
}

// async global->LDS, 16B per lane. LDS dest must be wave-uniform base + lane*16.
__device__ inline void gl_lds16(const u16* g, u16* l) {
    __builtin_amdgcn_global_load_lds(
        (const __attribute__((address_space(1))) u32*)g,
        (__attribute__((address_space(3))) u32*)l, 16, 0, 0);
}

// ---------------------------------------------------------------------------
// prep (merged): blocks 0..255 = G transpose tiles + per-jtile rowsum partials
//                blocks 256..767 = Q/Kw transpose-cast
__global__ __launch_bounds__(256) void prep(
        const float* __restrict__ G, const float* __restrict__ Q,
        const float* __restrict__ Kw, u16* __restrict__ Gbt,
        float* __restrict__ Grp, u16* __restrict__ QT, u16* __restrict__ KwT) {
    int bid = blockIdx.x;
    if (bid >= 256) {
        int idx = (bid - 256) * 256 + threadIdx.x;      // 0 .. 131071
        const float* src = (idx < 65536) ? Q : Kw;
        u16* dst = (idx < 65536) ? QT : KwT;
        int i = idx & 65535;
        int h = i >> 10;         // 0..63
        int n = i & 1023;        // 0..1023 (contiguous store)
        dst[h * 1024 + n] = f2bf(src[n * 64 + h]);
        return;
    }
    __shared__ float tile[64][65];
    int jt = bid & 15, it = bid >> 4;
    int i0 = it * 64, j0 = jt * 64;
    int tx = threadIdx.x & 63, ty = threadIdx.x >> 6;   // ty 0..3
    for (int r = 0; r < 16; ++r) {
        int i = ty * 16 + r;
        tile[i][tx] = G[(size_t)(i0 + i) * 1024 + j0 + tx];
    }
    __syncthreads();
    for (int r = 0; r < 16; ++r) {
        int j = ty * 16 + r;
        Gbt[(size_t)(j0 + j) * 1024 + i0 + tx] = f2bf(tile[tx][j]);
    }
    if (ty == 0) {
        float sum = 0.f;
        for (int j = 0; j < 64; ++j) sum += tile[tx][j];
        Grp[jt * 1024 + i0 + tx] = sum;                 // plain store, no atomics
    }
}

// ---------------------------------------------------------------------------
// qkt (merged): z==0 -> q[b][n][h] = sum_i s[n][b][i] Qw[i][h]
//               z==1 -> kt[b][i][h] = sum_n s[n][b][i] Kw[n][h]
// 512 blocks total -> 2 blocks/CU, 4 waves/SIMD (vs 1 block/CU when separate).
// z==0, y==0 blocks also finalize Grsum from the prep partials.
__global__ __launch_bounds__(512, 4) void qkt(
        const float* __restrict__ s, const u16* __restrict__ QT,
        const u16* __restrict__ KwT, const float* __restrict__ Grp,
        u16* __restrict__ qws, u16* __restrict__ ktws, float* __restrict__ Grsum) {
    int b = blockIdx.y;
    int t = threadIdx.x, lane = t & 63, w = t >> 6, quad = lane >> 4, l15 = lane & 15;
    __shared__ __align__(16) u16 sh[2][2][64][34];     // kt staging; q aliases as 16KB reduce
    float* red = (float*)sh;

    if (blockIdx.z == 0) {
        // ---------------- q role ----------------
        if (blockIdx.y == 0 && t < 64) {               // Grsum finalize (16 x-blocks cover 1024 i)
            int i = blockIdx.x * 64 + t;
            float g = 0.f;
            for (int jt = 0; jt < 16; ++jt) g += Grp[jt * 1024 + i];
            Grsum[i] = g;
        }
        int n0 = blockIdx.x * 64;
        int wm = (w & 3) * 16;                         // m-quarter within 64
        int kb = (w >> 2) * 512;                       // k-half
        const float* arow = s + (size_t)(n0 + wm + l15) * (BATCH * IN_DIM)
                              + (size_t)b * IN_DIM + kb + quad * 8;
        const u16* bbase = QT + (size_t)l15 * 1024 + kb + quad * 8;

        f32x4 acc[4] = {};
        float4 A0[3], A1[3];
        bf16x8 Bf[2][4];
        A0[0] = ((const float4*)arow)[0];
        A1[0] = ((const float4*)arow)[1];
        A0[1] = ((const float4*)(arow + 32))[0];
        A1[1] = ((const float4*)(arow + 32))[1];
#pragma unroll
        for (int ct = 0; ct < 4; ++ct)
            Bf[0][ct] = *(const bf16x8*)&bbase[ct * 16384];

#pragma unroll
        for (int st = 0; st < 16; ++st) {              // 16 steps of k=32
            int cur = st % 3, cb = st & 1;
            if (st < 14) {                             // A prefetch depth 3 (HBM)
                const float4* ap = (const float4*)(arow + (size_t)(st + 2) * 32);
                A0[(st + 2) % 3] = ap[0];
                A1[(st + 2) % 3] = ap[1];
            }
            if (st < 15) {                             // B prefetch depth 2 (L2)
#pragma unroll
                for (int ct = 0; ct < 4; ++ct)
                    Bf[cb ^ 1][ct] = *(const bf16x8*)&bbase[ct * 16384 + (st + 1) * 32];
            }
            float4 fa = A0[cur], fb = A1[cur];
            union { uint4 u; bf16x8 v; } cu;
            cu.u = (uint4){ pack2(fa.x, fa.y), pack2(fa.z, fa.w),
                            pack2(fb.x, fb.y), pack2(fb.z, fb.w) };
#pragma unroll
            for (int ct = 0; ct < 4; ++ct)
                acc[ct] = __builtin_amdgcn_mfma_f32_16x16x32_bf16(cu.v, Bf[cb][ct], acc[ct], 0, 0, 0);
        }

        // cross-k-half reduce through LDS
        if (w >= 4) {
            float* dst = red + ((w - 4) * 64 + lane) * 16;
#pragma unroll
            for (int ct = 0; ct < 4; ++ct) *(f32x4*)&dst[ct * 4] = acc[ct];
        }
        __syncthreads();
        if (w < 4) {
            const float* sp2 = red + (w * 64 + lane) * 16;
            u16* ob = qws + (size_t)b * 65536;
#pragma unroll
            for (int ct = 0; ct < 4; ++ct) {
                f32x4 o = *(const f32x4*)&sp2[ct * 4];
#pragma unroll
                for (int r = 0; r < 4; ++r) {
                    int m = n0 + wm + quad * 4 + r;
                    ob[(size_t)m * 64 + ct * 16 + l15] = f2bf(acc[ct][r] + o[r]);
                }
            }
        }
        return;
    }

    // ---------------- kt role ----------------
    int i0 = blockIdx.x * 64;
    int half = w >> 2;                                 // compute n-half
    int wm = (w & 3) * 16;                             // i-quarter
    int shalf = t >> 8, nr = (t & 255) >> 3, iofs = (t & 7) * 8;  // staging role
    const float* sp = s + (size_t)(shalf * 512 + nr) * (BATCH * IN_DIM)
                        + (size_t)b * IN_DIM + i0 + iofs;
    const u16* bbase = KwT + (size_t)l15 * 1024 + half * 512 + quad * 8;

    f32x4 acc[4] = {};
    float4 P0[2], P1[2];
    bf16x8 Bf[2][4];
    P0[0] = ((const float4*)sp)[0];
    P1[0] = ((const float4*)sp)[1];
    {
        const float4* p = (const float4*)(sp + (size_t)32 * 16384);
        P0[1] = p[0]; P1[1] = p[1];
    }
#pragma unroll
    for (int ct = 0; ct < 4; ++ct)
        Bf[0][ct] = *(const bf16x8*)&bbase[ct * 16384];

#pragma unroll
    for (int c = 0; c < 16; ++c) {                     // 16 chunks of n=32 per half
        int buf = c & 1;
        float4 fa = P0[buf], fb = P1[buf];
        u16* wp = &sh[shalf][buf][iofs][nr];
        wp[0]   = f2bf(fa.x);
        wp[34]  = f2bf(fa.y);
        wp[68]  = f2bf(fa.z);
        wp[102] = f2bf(fa.w);
        wp[136] = f2bf(fb.x);
        wp[170] = f2bf(fb.y);
        wp[204] = f2bf(fb.z);
        wp[238] = f2bf(fb.w);
        __syncthreads();                               // buf ready (both halves)
        if (c < 14) {                                  // prefetch chunk c+2 (HBM/L3)
            const float4* p = (const float4*)(sp + (size_t)(c + 2) * 32 * 16384);
            P0[buf] = p[0]; P1[buf] = p[1];
        }
        if (c < 15) {                                  // prefetch next B-frags (L2)
#pragma unroll
            for (int ct = 0; ct < 4; ++ct)
                Bf[(c + 1) & 1][ct] = *(const bf16x8*)&bbase[ct * 16384 + (c + 1) * 32];
        }
        const u32* ap = (const u32*)&sh[half][buf][wm + l15][quad * 8];
        union { u32 u[4]; bf16x8 v; } au;
        au.u[0] = ap[0]; au.u[1] = ap[1]; au.u[2] = ap[2]; au.u[3] = ap[3];
#pragma unroll
        for (int ct = 0; ct < 4; ++ct)
            acc[ct] = __builtin_amdgcn_mfma_f32_16x16x32_bf16(au.v, Bf[buf][ct], acc[ct], 0, 0, 0);
    }

    __syncthreads();                                   // staging reads all done
    if (w >= 4) {
        float* dst = red + ((w - 4) * 64 + lane) * 16;
#pragma unroll
        for (int ct = 0; ct < 4; ++ct) *(f32x4*)&dst[ct * 4] = acc[ct];
    }
    __syncthreads();
    if (w < 4) {
        const float* sp2 = red + (w * 64 + lane) * 16;
        u16* ob = ktws + (size_t)b * 65536;
#pragma unroll
        for (int ct = 0; ct < 4; ++ct) {
            f32x4 o = *(const f32x4*)&sp2[ct * 4];
#pragma unroll
            for (int r = 0; r < 4; ++r) {
                int i = i0 + wm + quad * 4 + r;
                ob[(size_t)i * 64 + ct * 16 + l15] = f2bf(acc[ct][r] + o[r]);
            }
        }
    }
}

// ---------------------------------------------------------------------------
// gemm_fused (BN=256): per (b, m-tile 128, n-tile 256):
//   K-loop over i (32/step): score chunk S^T(32i x 128m) = kt_chunk @ q^T (MFMA),
//   square(+1e-9), rowsum via Grsum identity, pack bf16 -> As (padded), then
//   agg k-step: acc += As(128x32) @ Gbt-chunk(256 rows). Epilogue: scale by
//   1/(rowsum+1e-3), write transposed (n,B,j) fp32 output. att never hits HBM.
// Bs (Gbt staging) uses a both-sides XOR swizzle: gl_lds dest is linear (HW
// constraint), the SOURCE 16B-slot is permuted slot^(row&3), and the agg read
// applies the same involution -> 8-way bank conflict becomes 2-way (free).
__global__ __launch_bounds__(256, 2) void gemm_fused(
        const u16* __restrict__ qws, const u16* __restrict__ ktws,
        const u16* __restrict__ Gbt, const float* __restrict__ Grsum,
        float* __restrict__ out) {
    int b = blockIdx.z;
    int n0 = blockIdx.x * 256, m0 = blockIdx.y * 128;
    const u16* qb = qws  + (size_t)b * 65536;
    const u16* kb = ktws + (size_t)b * 65536;
    __shared__ __align__(16) u16 As[128 * 40];       // score->agg buffer, padded
    __shared__ __align__(16) u16 Bs[2][256 * 32];    // Gbt staging (gl_lds, dbuf, swizzled)
    __shared__ __align__(16) u16 ktc[32 * 72];       // kt chunk, padded, single buf
    __shared__ __align__(16) float Grs[1024];
    __shared__ float rs[128];
    int t = threadIdx.x, lane = t & 63, w = t >> 6, quad = lane >> 4, l15 = lane & 15;
    int ti = w & 1;                              // score i-subtile (16 of 32)
    int wm = (w >> 1) * 64;                      // m-half (shared by score & agg)
    int wn = (w & 1) * 128;                      // agg n-half of 256

    ((float4*)Grs)[t] = ((const float4*)Grsum)[t];
    if (t < 128) rs[t] = 0.f;

    // K-invariant q B-frags: B[k=h][col=m], 8 contiguous h per lane
    bf16x8 qf[4][2];
    for (int j = 0; j < 4; ++j)
        for (int kick = 0; kick < 2; ++kick)
            qf[j][kick] = *(const bf16x8*)&qb[(size_t)(m0 + wm + j*16 + l15) * 64 + kick*32 + quad*8];

    // staging geometry: row = br+g4*64, source 16B-slot swizzled by row&3
    int br = t >> 2, bc = ((t & 3) ^ (br & 3)) * 8;
    for (int g4 = 0; g4 < 4; ++g4)
        gl_lds16(Gbt + (size_t)(n0 + br + g4*64) * 1024 + bc, &Bs[0][(br + g4*64) * 32 + (t & 3) * 8]);
    int ir = t >> 3, ch = (t & 7) * 8;
    uint4 kreg = *(const uint4*)&kb[(size_t)ir * 64 + ch];
    int khs = (quad ^ (l15 & 3)) * 8;            // swizzled agg B-read slot (per-lane const)

    f32x4 acc[4][8] = {};
    float partial[4] = {0.f, 0.f, 0.f, 0.f};

    for (int kk = 0; kk < 32; ++kk) {
        int buf = kk & 1;
        *(uint4*)&ktc[ir * 72 + ch] = kreg;        // single buf: prev reads done pre-barrier2
        __syncthreads();                           // barrier1: Bs[buf] + ktc ready
        // ---- score: S^T[i][m] for i-subtile ti, m in wave's 64-half
        f32x4 sacc[4] = {};
        for (int kick = 0; kick < 2; ++kick) {
            bf16x8 ktf = *(const bf16x8*)&ktc[(ti*16 + l15) * 72 + kick*32 + quad*8];
            for (int j = 0; j < 4; ++j)
                sacc[j] = __builtin_amdgcn_mfma_f32_16x16x32_bf16(ktf, qf[j][kick], sacc[j], 0, 0, 0);
        }
        if (kk < 31)
            kreg = *(const uint4*)&kb[(size_t)((kk + 1) * 32 + ir) * 64 + ch];
        // ---- epilogue: square, rowsum partial, pack to As
        float4 g = *(const float4*)&Grs[kk * 32 + ti * 16 + quad * 4];
        for (int j = 0; j < 4; ++j) {
            float v0 = sacc[j][0] * 0.125f + 1e-9f; v0 *= v0;
            float v1 = sacc[j][1] * 0.125f + 1e-9f; v1 *= v1;
            float v2 = sacc[j][2] * 0.125f + 1e-9f; v2 *= v2;
            float v3 = sacc[j][3] * 0.125f + 1e-9f; v3 *= v3;
            partial[j] += v0 * g.x + v1 * g.y + v2 * g.z + v3 * g.w;
            uint2 pk = { pack2(v0, v1), pack2(v2, v3) };
            *(uint2*)&As[(wm + j*16 + l15) * 40 + ti*16 + quad*4] = pk;
        }
        __syncthreads();                           // barrier2: As ready
        if (kk < 31) {                             // prefetch next Gbt chunk (in flight across agg)
            for (int g4 = 0; g4 < 4; ++g4)
                gl_lds16(Gbt + (size_t)(n0 + br + g4*64) * 1024 + (kk+1)*32 + bc,
                         &Bs[buf^1][(br + g4*64) * 32 + (t & 3) * 8]);
        }
        // ---- agg k-step: wave's 64m x 128n
        int kh = quad * 8;
        bf16x8 af[4];
        for (int i = 0; i < 4; ++i) af[i] = *(const bf16x8*)&As[(wm + i*16 + l15) * 40 + kh];
        for (int jh = 0; jh < 2; ++jh) {
            bf16x8 bfr[4];
            for (int j = 0; j < 4; ++j)
                bfr[j] = *(const bf16x8*)&Bs[buf][(wn + jh*64 + j*16 + l15) * 32 + khs];
            for (int i = 0; i < 4; ++i)
                for (int j = 0; j < 4; ++j)
                    acc[i][jh*4 + j] = __builtin_amdgcn_mfma_f32_16x16x32_bf16(af[i], bfr[j], acc[i][jh*4 + j], 0, 0, 0);
        }
    }

    // rowsum: reduce quads (same m, different i-subsets), combine waves via LDS
    for (int j = 0; j < 4; ++j) {
        partial[j] += __shfl_xor(partial[j], 16, 64);
        partial[j] += __shfl_xor(partial[j], 32, 64);
    }
    if (quad == 0)
        for (int j = 0; j < 4; ++j) atomicAdd(&rs[wm + j*16 + l15], partial[j]);
    __syncthreads();
    if (t < 128) rs[t] = 1.0f / (rs[t] + 0.001f);
    __syncthreads();

    for (int i = 0; i < 4; ++i) {
        float4 rv = *(const float4*)&rs[wm + i * 16 + quad * 4];
        float rva[4] = { rv.x, rv.y, rv.z, rv.w };
        for (int r = 0; r < 4; ++r) {
            int m = m0 + wm + i * 16 + quad * 4 + r;
            float* orow = out + (size_t)m * (BATCH * IN_DIM) + (size_t)b * IN_DIM + n0 + wn;
            for (int j = 0; j < 8; ++j)
                orow[j * 16 + l15] = acc[i][j][r] * rva[r];
        }
    }
}

// ---------------------------------------------------------------------------
extern "C" void kernel_launch(void* const* d_in, const int* in_sizes, int n_in,
                              void* d_out, int out_size, void* d_ws, size_t ws_size,
                              hipStream_t stream) {
    const float* s  = (const float*)d_in[0];
    const float* G  = (const float*)d_in[1];
    const float* Q  = (const float*)d_in[2];
    const float* Kw = (const float*)d_in[3];
    float* out = (float*)d_out;
    char* ws = (char*)d_ws;

    u16*   qws   = (u16*)(ws);                                    // 2 MB
    u16*   ktws  = (u16*)(ws + (size_t)(2u << 20));               // 2 MB
    u16*   Gbt   = (u16*)(ws + (size_t)(4u << 20));               // 2 MB
    u16*   QT    = (u16*)(ws + (size_t)(6u << 20));               // 128 KB
    u16*   KwT   = (u16*)(ws + (size_t)(6u << 20) + (128u << 10)); // 128 KB
    float* Grsum = (float*)(ws + (size_t)(6u << 20) + (256u << 10)); // 4 KB
    float* Grp   = (float*)(ws + (size_t)(6u << 20) + (260u << 10)); // 64 KB

    prep<<<768, 256, 0, stream>>>(G, Q, Kw, Gbt, Grp, QT, KwT);
    qkt<<<dim3(16, 16, 2), 512, 0, stream>>>(s, QT, KwT, Grp, qws, ktws, Grsum);
    gemm_fused<<<dim3(4, 8, 16), 256, 0, stream>>>(qws, ktws, Gbt, Grsum, out);
}